// Round 2
// 418.351 us; speedup vs baseline: 1.0453x; 1.0453x over previous
//
#include <hip/hip_runtime.h>
#include <stdint.h>

#define T_TOK 2048
#define DIM   2048
#define FDIM  1024
#define NE    8
#define MAXTILES 40

typedef __attribute__((ext_vector_type(8))) short short8;
typedef __attribute__((ext_vector_type(4))) float f32x4;

__device__ __forceinline__ unsigned short f2b(float f) {
  union { float f; unsigned int i; } x; x.f = f;
  unsigned int r = x.i + 0x7fffu + ((x.i >> 16) & 1u);
  return (unsigned short)(r >> 16);
}

__device__ __forceinline__ void async16(void* lds, const void* g) {
  __builtin_amdgcn_global_load_lds(
      (const __attribute__((address_space(1))) void*)g,
      (__attribute__((address_space(3))) void*)lds, 16, 0, 0);
}

// ---------------- weight convert: fp32 -> bf16 (pure streaming) ----------------
__global__ __launch_bounds__(256) void cvt_w_k(const float* __restrict__ src,
                                               unsigned short* __restrict__ dst)
{
  size_t i = ((size_t)blockIdx.x * 256 + threadIdx.x) * 8;
  float4 a = *(const float4*)(src + i);
  float4 b = *(const float4*)(src + i + 4);
  ushort4 o0, o1;
  o0.x = f2b(a.x); o0.y = f2b(a.y); o0.z = f2b(a.z); o0.w = f2b(a.w);
  o1.x = f2b(b.x); o1.y = f2b(b.y); o1.z = f2b(b.z); o1.w = f2b(b.w);
  *(ushort4*)(dst + i) = o0;
  *(ushort4*)(dst + i + 4) = o1;
}

// ---------------- router: fp32 logits, softmax, top-2, renorm; fused x->bf16 ----------------
__global__ __launch_bounds__(256) void router_k(
    const float* __restrict__ x, const float* __restrict__ gw,
    float* __restrict__ topkw, int* __restrict__ topke, int* __restrict__ counts,
    float* __restrict__ logits_out, unsigned short* __restrict__ xb)
{
  int wave = threadIdx.x >> 6, lane = threadIdx.x & 63;
  int t = blockIdx.x * 4 + wave;
  const float* xr = x + (size_t)t * DIM;
  unsigned short* xbr = xb + (size_t)t * DIM;
  float acc[NE];
#pragma unroll
  for (int e = 0; e < NE; e++) acc[e] = 0.f;
  for (int d = lane * 4; d < DIM; d += 256) {
    float4 xv = *(const float4*)(xr + d);
    ushort4 xo;
    xo.x = f2b(xv.x); xo.y = f2b(xv.y); xo.z = f2b(xv.z); xo.w = f2b(xv.w);
    *(ushort4*)(xbr + d) = xo;
#pragma unroll
    for (int e = 0; e < NE; e++) {
      float4 gv = *(const float4*)(gw + e * DIM + d);
      acc[e] += xv.x * gv.x + xv.y * gv.y + xv.z * gv.z + xv.w * gv.w;
    }
  }
#pragma unroll
  for (int off = 32; off > 0; off >>= 1) {
#pragma unroll
    for (int e = 0; e < NE; e++) acc[e] += __shfl_down(acc[e], off);
  }
  if (lane == 0) {
    float m = acc[0];
#pragma unroll
    for (int e = 1; e < NE; e++) m = fmaxf(m, acc[e]);
    float p[NE];
#pragma unroll
    for (int e = 0; e < NE; e++) p[e] = __expf(acc[e] - m);
    int e0 = 0;
#pragma unroll
    for (int e = 1; e < NE; e++) if (acc[e] > acc[e0]) e0 = e;
    int e1 = -1;
#pragma unroll
    for (int e = 0; e < NE; e++) if (e != e0 && (e1 < 0 || acc[e] > acc[e1])) e1 = e;
    float s = p[e0] + p[e1];
    topkw[t * 2] = p[e0] / s;
    topkw[t * 2 + 1] = p[e1] / s;
    topke[t * 2] = e0; topke[t * 2 + 1] = e1;
    atomicAdd(&counts[e0], 1);
    atomicAdd(&counts[e1], 1);
#pragma unroll
    for (int e = 0; e < NE; e++) logits_out[t * NE + e] = acc[e];
  }
}

// ---------------- scan: offsets, cursors, tile table ----------------
__global__ void scan_k(const int* __restrict__ counts, int* __restrict__ offsets,
                       int* __restrict__ cursors, int4* __restrict__ tiles,
                       int* __restrict__ ntiles)
{
  if (threadIdx.x == 0 && blockIdx.x == 0) {
    int o = 0, nt = 0;
    for (int e = 0; e < NE; e++) {
      offsets[e] = o; cursors[e] = o;
      int c = counts[e];
      for (int r = 0; r < c; r += 128) {
        int rows = c - r < 128 ? c - r : 128;
        tiles[nt] = make_int4(e, o + r, rows, 0);
        nt++;
      }
      o += c;
    }
    offsets[NE] = o;
    *ntiles = nt;
  }
}

// ---------------- scatter: (t,k) -> sorted slot ----------------
__global__ void scatter_k(const int* __restrict__ topke, int* __restrict__ cursors,
                          int* __restrict__ perm)
{
  int i = blockIdx.x * blockDim.x + threadIdx.x;
  int e = topke[i];
  int s = atomicAdd(&cursors[e], 1);
  perm[s] = i;
}

// ================= bf16-weight path (primary) =================

// GEMM1: H[slot,f] = rw * silu(x@Wg^T) * (x@Wu^T); all operands bf16 via global_load_lds
__global__ __launch_bounds__(256) void gemm1_bf_k(
    const unsigned short* __restrict__ xb,
    const unsigned short* __restrict__ wgb,
    const unsigned short* __restrict__ wub,
    const int* __restrict__ perm, const float* __restrict__ topkw,
    const int4* __restrict__ tiles, const int* __restrict__ ntiles,
    unsigned short* __restrict__ H)
{
  __shared__ short As[128 * 32];
  __shared__ short Bgs[64 * 32];
  __shared__ short Bus[64 * 32];
  __shared__ int rowtok[128];
  __shared__ float roww[128];

  if (blockIdx.x >= *ntiles) return;
  int4 tm = tiles[blockIdx.x];
  int e = tm.x, row0 = tm.y, nrows = tm.z;
  int tid = threadIdx.x;
  if (tid < 128) {
    int r = tid < nrows ? tid : (nrows - 1);
    int pid = perm[row0 + r];
    rowtok[tid] = pid >> 1;
    roww[tid] = topkw[pid];
  }
  __syncthreads();

  int f0 = blockIdx.y * 64;
  int crow = tid >> 2;            // 0..63
  int ccol = (tid & 3) * 8;       // 8-elem chunk offset
  const unsigned short* a0 = xb + (size_t)rowtok[crow] * DIM + ccol;
  const unsigned short* a1 = xb + (size_t)rowtok[crow + 64] * DIM + ccol;
  const unsigned short* bg = wgb + ((size_t)e * FDIM + f0 + crow) * DIM + ccol;
  const unsigned short* bu = wub + ((size_t)e * FDIM + f0 + crow) * DIM + ccol;
  short* as0 = As + tid * 8;
  short* as1 = As + (256 + tid) * 8;
  short* bgs = Bgs + tid * 8;
  short* bus = Bus + tid * 8;

  int wave = tid >> 6, lane = tid & 63;
  int wm = wave >> 1, wn = wave & 1;
  int lrow = lane & 15, quad = lane >> 4;

  f32x4 accg[4][2], accu[4][2];
#pragma unroll
  for (int i = 0; i < 4; i++)
#pragma unroll
    for (int j = 0; j < 2; j++) {
      accg[i][j] = (f32x4){0.f, 0.f, 0.f, 0.f};
      accu[i][j] = (f32x4){0.f, 0.f, 0.f, 0.f};
    }

  const short* arp = As + (wm * 64 + lrow) * 32 + quad * 8;
  const short* bgp = Bgs + (wn * 32 + lrow) * 32 + quad * 8;
  const short* bup = Bus + (wn * 32 + lrow) * 32 + quad * 8;

#pragma unroll 1
  for (int k0 = 0; k0 < DIM; k0 += 32) {
    async16(as0, a0 + k0);
    async16(as1, a1 + k0);
    async16(bgs, bg + k0);
    async16(bus, bu + k0);
    __syncthreads();
    short8 af[4], bgf[2], buf2[2];
#pragma unroll
    for (int i = 0; i < 4; i++) af[i] = *(const short8*)(arp + i * 16 * 32);
#pragma unroll
    for (int j = 0; j < 2; j++) {
      bgf[j]  = *(const short8*)(bgp + j * 16 * 32);
      buf2[j] = *(const short8*)(bup + j * 16 * 32);
    }
#pragma unroll
    for (int i = 0; i < 4; i++)
#pragma unroll
      for (int j = 0; j < 2; j++) {
        accg[i][j] = __builtin_amdgcn_mfma_f32_16x16x32_bf16(af[i], bgf[j], accg[i][j], 0, 0, 0);
        accu[i][j] = __builtin_amdgcn_mfma_f32_16x16x32_bf16(af[i], buf2[j], accu[i][j], 0, 0, 0);
      }
    __syncthreads();
  }

#pragma unroll
  for (int i = 0; i < 4; i++) {
#pragma unroll
    for (int reg = 0; reg < 4; reg++) {
      int r = wm * 64 + i * 16 + quad * 4 + reg;
      if (r < nrows) {
        float w = roww[r];
#pragma unroll
        for (int j = 0; j < 2; j++) {
          float g = accg[i][j][reg], u = accu[i][j][reg];
          float h = g * u * w / (1.f + __expf(-g));
          H[(size_t)(row0 + r) * FDIM + f0 + wn * 32 + j * 16 + lrow] = f2b(h);
        }
      }
    }
  }
}

// GEMM2: out[t,d] += H[slot,:] @ Wd[e]^T  (128x128 tile, fp32 atomics)
__global__ __launch_bounds__(256) void gemm2_bf_k(
    const unsigned short* __restrict__ H,
    const unsigned short* __restrict__ wdb,
    const int* __restrict__ perm,
    const int4* __restrict__ tiles, const int* __restrict__ ntiles,
    float* __restrict__ out)
{
  __shared__ short Hs[128 * 32];
  __shared__ short Bs[128 * 32];
  __shared__ int rowtok[128];

  if (blockIdx.x >= *ntiles) return;
  int4 tm = tiles[blockIdx.x];
  int e = tm.x, row0 = tm.y, nrows = tm.z;
  int tid = threadIdx.x;
  if (tid < 128) {
    int r = tid < nrows ? tid : (nrows - 1);
    rowtok[tid] = perm[row0 + r] >> 1;
  }
  __syncthreads();

  int d0 = blockIdx.y * 128;
  int crow = tid >> 2, ccol = (tid & 3) * 8;
  const unsigned short* a0 = H + (size_t)(row0 + crow) * FDIM + ccol;
  const unsigned short* a1 = H + (size_t)(row0 + crow + 64) * FDIM + ccol;
  const unsigned short* b0 = wdb + ((size_t)e * DIM + d0 + crow) * FDIM + ccol;
  const unsigned short* b1 = b0 + (size_t)64 * FDIM;
  short* hs0 = Hs + tid * 8;
  short* hs1 = Hs + (256 + tid) * 8;
  short* bs0 = Bs + tid * 8;
  short* bs1 = Bs + (256 + tid) * 8;

  int wave = tid >> 6, lane = tid & 63;
  int wm = wave >> 1, wn = wave & 1;
  int lrow = lane & 15, quad = lane >> 4;

  f32x4 acc[4][4];
#pragma unroll
  for (int i = 0; i < 4; i++)
#pragma unroll
    for (int j = 0; j < 4; j++) acc[i][j] = (f32x4){0.f, 0.f, 0.f, 0.f};

  const short* arp = Hs + (wm * 64 + lrow) * 32 + quad * 8;
  const short* brp = Bs + (wn * 64 + lrow) * 32 + quad * 8;

#pragma unroll 1
  for (int k0 = 0; k0 < FDIM; k0 += 32) {
    async16(hs0, a0 + k0);
    async16(hs1, a1 + k0);
    async16(bs0, b0 + k0);
    async16(bs1, b1 + k0);
    __syncthreads();
    short8 af[4], bf[4];
#pragma unroll
    for (int i = 0; i < 4; i++) af[i] = *(const short8*)(arp + i * 16 * 32);
#pragma unroll
    for (int j = 0; j < 4; j++) bf[j] = *(const short8*)(brp + j * 16 * 32);
#pragma unroll
    for (int i = 0; i < 4; i++)
#pragma unroll
      for (int j = 0; j < 4; j++)
        acc[i][j] = __builtin_amdgcn_mfma_f32_16x16x32_bf16(af[i], bf[j], acc[i][j], 0, 0, 0);
    __syncthreads();
  }

#pragma unroll
  for (int i = 0; i < 4; i++) {
#pragma unroll
    for (int reg = 0; reg < 4; reg++) {
      int r = wm * 64 + i * 16 + quad * 4 + reg;
      if (r < nrows) {
        int t = rowtok[r];
#pragma unroll
        for (int j = 0; j < 4; j++) {
          atomicAdd(&out[(size_t)t * DIM + d0 + wn * 64 + j * 16 + lrow], acc[i][j][reg]);
        }
      }
    }
  }
}

// ================= fp32-weight fallback path (proven, used if ws too small) =================

__global__ __launch_bounds__(256) void gemm1_f32_k(
    const unsigned short* __restrict__ xb,
    const float* __restrict__ wg,
    const float* __restrict__ wu,
    const int* __restrict__ perm, const float* __restrict__ topkw,
    const int4* __restrict__ tiles, const int* __restrict__ ntiles,
    unsigned short* __restrict__ H)
{
  __shared__ short As[128 * 32];
  __shared__ short Bgs[64 * 32];
  __shared__ short Bus[64 * 32];
  __shared__ int rowtok[128];
  __shared__ float roww[128];

  if (blockIdx.x >= *ntiles) return;
  int4 tm = tiles[blockIdx.x];
  int e = tm.x, row0 = tm.y, nrows = tm.z;
  int tid = threadIdx.x;
  if (tid < 128) {
    int r = tid < nrows ? tid : (nrows - 1);
    int pid = perm[row0 + r];
    rowtok[tid] = pid >> 1;
    roww[tid] = topkw[pid];
  }
  __syncthreads();

  int f0 = blockIdx.y * 64;
  int crow = tid >> 2;
  int ccol = (tid & 3) * 8;
  const unsigned short* a0 = xb + (size_t)rowtok[crow] * DIM + ccol;
  const unsigned short* a1 = xb + (size_t)rowtok[crow + 64] * DIM + ccol;
  const float* bg32 = wg + ((size_t)e * FDIM + f0 + crow) * DIM + ccol;
  const float* bu32 = wu + ((size_t)e * FDIM + f0 + crow) * DIM + ccol;
  short* as0 = As + tid * 8;
  short* as1 = As + (256 + tid) * 8;

  int wave = tid >> 6, lane = tid & 63;
  int wm = wave >> 1, wn = wave & 1;
  int lrow = lane & 15, quad = lane >> 4;

  f32x4 accg[4][2], accu[4][2];
#pragma unroll
  for (int i = 0; i < 4; i++)
#pragma unroll
    for (int j = 0; j < 2; j++) {
      accg[i][j] = (f32x4){0.f, 0.f, 0.f, 0.f};
      accu[i][j] = (f32x4){0.f, 0.f, 0.f, 0.f};
    }

  const short* arp = As + (wm * 64 + lrow) * 32 + quad * 8;
  const short* bgp = Bgs + (wn * 32 + lrow) * 32 + quad * 8;
  const short* bup = Bus + (wn * 32 + lrow) * 32 + quad * 8;

#pragma unroll 1
  for (int k0 = 0; k0 < DIM; k0 += 32) {
    async16(as0, a0 + k0);
    async16(as1, a1 + k0);
    float4 g0 = *(const float4*)(bg32 + k0);
    float4 g1 = *(const float4*)(bg32 + k0 + 4);
    float4 u0 = *(const float4*)(bu32 + k0);
    float4 u1 = *(const float4*)(bu32 + k0 + 4);
    short8 gs, us;
    gs[0] = f2b(g0.x); gs[1] = f2b(g0.y); gs[2] = f2b(g0.z); gs[3] = f2b(g0.w);
    gs[4] = f2b(g1.x); gs[5] = f2b(g1.y); gs[6] = f2b(g1.z); gs[7] = f2b(g1.w);
    us[0] = f2b(u0.x); us[1] = f2b(u0.y); us[2] = f2b(u0.z); us[3] = f2b(u0.w);
    us[4] = f2b(u1.x); us[5] = f2b(u1.y); us[6] = f2b(u1.z); us[7] = f2b(u1.w);
    *(short8*)(Bgs + tid * 8) = gs;
    *(short8*)(Bus + tid * 8) = us;
    __syncthreads();
    short8 af[4], bgf[2], buf2[2];
#pragma unroll
    for (int i = 0; i < 4; i++) af[i] = *(const short8*)(arp + i * 16 * 32);
#pragma unroll
    for (int j = 0; j < 2; j++) {
      bgf[j]  = *(const short8*)(bgp + j * 16 * 32);
      buf2[j] = *(const short8*)(bup + j * 16 * 32);
    }
#pragma unroll
    for (int i = 0; i < 4; i++)
#pragma unroll
      for (int j = 0; j < 2; j++) {
        accg[i][j] = __builtin_amdgcn_mfma_f32_16x16x32_bf16(af[i], bgf[j], accg[i][j], 0, 0, 0);
        accu[i][j] = __builtin_amdgcn_mfma_f32_16x16x32_bf16(af[i], buf2[j], accu[i][j], 0, 0, 0);
      }
    __syncthreads();
  }

#pragma unroll
  for (int i = 0; i < 4; i++) {
#pragma unroll
    for (int reg = 0; reg < 4; reg++) {
      int r = wm * 64 + i * 16 + quad * 4 + reg;
      if (r < nrows) {
        float w = roww[r];
#pragma unroll
        for (int j = 0; j < 2; j++) {
          float g = accg[i][j][reg], u = accu[i][j][reg];
          float h = g * u * w / (1.f + __expf(-g));
          H[(size_t)(row0 + r) * FDIM + f0 + wn * 32 + j * 16 + lrow] = f2b(h);
        }
      }
    }
  }
}

__global__ __launch_bounds__(256) void gemm2_f32_k(
    const unsigned short* __restrict__ H,
    const float* __restrict__ wd,
    const int* __restrict__ perm,
    const int4* __restrict__ tiles, const int* __restrict__ ntiles,
    float* __restrict__ out)
{
  __shared__ short Hs[128 * 32];
  __shared__ short Bs[64 * 32];
  __shared__ int rowtok[128];

  if (blockIdx.x >= *ntiles) return;
  int4 tm = tiles[blockIdx.x];
  int e = tm.x, row0 = tm.y, nrows = tm.z;
  int tid = threadIdx.x;
  if (tid < 128) {
    int r = tid < nrows ? tid : (nrows - 1);
    rowtok[tid] = perm[row0 + r] >> 1;
  }
  __syncthreads();

  int d0 = blockIdx.y * 64;
  int crow = tid >> 2, ccol = (tid & 3) * 8;
  const unsigned short* a0 = H + (size_t)(row0 + crow) * FDIM + ccol;
  const unsigned short* a1 = H + (size_t)(row0 + crow + 64) * FDIM + ccol;
  const float* b32 = wd + ((size_t)e * DIM + d0 + crow) * FDIM + ccol;
  short* hs0 = Hs + tid * 8;
  short* hs1 = Hs + (256 + tid) * 8;

  int wave = tid >> 6, lane = tid & 63;
  int wm = wave >> 1, wn = wave & 1;
  int lrow = lane & 15, quad = lane >> 4;

  f32x4 acc[4][2];
#pragma unroll
  for (int i = 0; i < 4; i++)
#pragma unroll
    for (int j = 0; j < 2; j++) acc[i][j] = (f32x4){0.f, 0.f, 0.f, 0.f};

  const short* arp = Hs + (wm * 64 + lrow) * 32 + quad * 8;
  const short* brp = Bs + (wn * 32 + lrow) * 32 + quad * 8;

#pragma unroll 1
  for (int k0 = 0; k0 < FDIM; k0 += 32) {
    async16(hs0, a0 + k0);
    async16(hs1, a1 + k0);
    float4 b0 = *(const float4*)(b32 + k0);
    float4 b1 = *(const float4*)(b32 + k0 + 4);
    short8 bsv;
    bsv[0] = f2b(b0.x); bsv[1] = f2b(b0.y); bsv[2] = f2b(b0.z); bsv[3] = f2b(b0.w);
    bsv[4] = f2b(b1.x); bsv[5] = f2b(b1.y); bsv[6] = f2b(b1.z); bsv[7] = f2b(b1.w);
    *(short8*)(Bs + tid * 8) = bsv;
    __syncthreads();
    short8 af[4], bf[2];
#pragma unroll
    for (int i = 0; i < 4; i++) af[i] = *(const short8*)(arp + i * 16 * 32);
#pragma unroll
    for (int j = 0; j < 2; j++) bf[j] = *(const short8*)(brp + j * 16 * 32);
#pragma unroll
    for (int i = 0; i < 4; i++)
#pragma unroll
      for (int j = 0; j < 2; j++)
        acc[i][j] = __builtin_amdgcn_mfma_f32_16x16x32_bf16(af[i], bf[j], acc[i][j], 0, 0, 0);
    __syncthreads();
  }

#pragma unroll
  for (int i = 0; i < 4; i++) {
#pragma unroll
    for (int reg = 0; reg < 4; reg++) {
      int r = wm * 64 + i * 16 + quad * 4 + reg;
      if (r < nrows) {
        int t = rowtok[r];
#pragma unroll
        for (int j = 0; j < 2; j++) {
          atomicAdd(&out[(size_t)t * DIM + d0 + wn * 32 + j * 16 + lrow], acc[i][j][reg]);
        }
      }
    }
  }
}

extern "C" void kernel_launch(void* const* d_in, const int* in_sizes, int n_in,
                              void* d_out, int out_size, void* d_ws, size_t ws_size,
                              hipStream_t stream)
{
  const float* x  = (const float*)d_in[0];
  const float* gw = (const float*)d_in[1];
  const float* wg = (const float*)d_in[2];
  const float* wu = (const float*)d_in[3];
  const float* wd = (const float*)d_in[4];
  float* out = (float*)d_out;
  float* logits_out = out + (size_t)T_TOK * DIM;

  char* ws = (char*)d_ws;
  float* topkw   = (float*)(ws + 0);                 // 16 KB
  int*   topke   = (int*)(ws + 16384);               // 16 KB
  int*   counts  = (int*)(ws + 32768);
  int*   offsets = (int*)(ws + 32768 + 64);
  int*   cursors = (int*)(ws + 32768 + 128);
  int*   ntiles  = (int*)(ws + 32768 + 192);
  int4*  tiles   = (int4*)(ws + 32768 + 256);        // <= 40 * 16 B
  int*   perm    = (int*)(ws + 32768 + 2048);        // 16 KB
  unsigned short* xb  = (unsigned short*)(ws + (1u << 16));      // 8 MiB bf16 x @64KiB
  unsigned short* H   = (unsigned short*)(ws + (9u  << 20));     // 8.65 MiB @9MiB
  unsigned short* wgb = (unsigned short*)(ws + (18u << 20));     // 32 MiB @18MiB
  unsigned short* wub = (unsigned short*)(ws + (50u << 20));     // 32 MiB @50MiB
  unsigned short* wdb = wgb;   // aliases wgb: gate weights dead after gemm1
  const size_t WS_NEED = (size_t)82u << 20;

  // d_out is poisoned (0xAA) before timed replays -> zero it ourselves.
  hipMemsetAsync(d_out, 0, (size_t)out_size * sizeof(float), stream);
  hipMemsetAsync(counts, 0, 64, stream);

  router_k<<<T_TOK / 4, 256, 0, stream>>>(x, gw, topkw, topke, counts, logits_out, xb);
  scan_k<<<1, 64, 0, stream>>>(counts, offsets, cursors, tiles, ntiles);
  scatter_k<<<(T_TOK * 2) / 256, 256, 0, stream>>>(topke, cursors, perm);

  if (ws_size >= WS_NEED) {
    const int nblk = (NE * FDIM * DIM) / 2048;   // 8192 blocks per weight tensor
    cvt_w_k<<<nblk, 256, 0, stream>>>(wg, wgb);
    cvt_w_k<<<nblk, 256, 0, stream>>>(wu, wub);
    gemm1_bf_k<<<dim3(MAXTILES, FDIM / 64), 256, 0, stream>>>(xb, wgb, wub, perm, topkw, tiles, ntiles, H);
    // wd conversion stream-ordered AFTER gemm1 (wdb aliases wgb)
    cvt_w_k<<<nblk, 256, 0, stream>>>(wd, wdb);
    gemm2_bf_k<<<dim3(MAXTILES, DIM / 128), 256, 0, stream>>>(H, wdb, perm, tiles, ntiles, out);
  } else {
    gemm1_f32_k<<<dim3(MAXTILES, FDIM / 64), 256, 0, stream>>>(xb, wg, wu, perm, topkw, tiles, ntiles, H);
    gemm2_f32_k<<<dim3(MAXTILES, DIM / 64), 256, 0, stream>>>(H, wd, perm, tiles, ntiles, out);
  }
}

// Round 3
// 407.604 us; speedup vs baseline: 1.0729x; 1.0264x over previous
//
#include <hip/hip_runtime.h>
#include <stdint.h>

#define T_TOK 2048
#define DIM   2048
#define FDIM  1024
#define NE    8
#define MAXTILES 40

typedef __attribute__((ext_vector_type(8))) short short8;
typedef __attribute__((ext_vector_type(4))) float f32x4;

__device__ __forceinline__ unsigned short f2b(float f) {
  union { float f; unsigned int i; } x; x.f = f;
  unsigned int r = x.i + 0x7fffu + ((x.i >> 16) & 1u);
  return (unsigned short)(r >> 16);
}

__device__ __forceinline__ void async16(void* lds, const void* g) {
  __builtin_amdgcn_global_load_lds(
      (const __attribute__((address_space(1))) void*)g,
      (__attribute__((address_space(3))) void*)lds, 16, 0, 0);
}

// ---------------- weight convert: fp32 -> bf16 (pure streaming) ----------------
__global__ __launch_bounds__(256) void cvt_w_k(const float* __restrict__ src,
                                               unsigned short* __restrict__ dst)
{
  size_t i = ((size_t)blockIdx.x * 256 + threadIdx.x) * 8;
  float4 a = *(const float4*)(src + i);
  float4 b = *(const float4*)(src + i + 4);
  ushort4 o0, o1;
  o0.x = f2b(a.x); o0.y = f2b(a.y); o0.z = f2b(a.z); o0.w = f2b(a.w);
  o1.x = f2b(b.x); o1.y = f2b(b.y); o1.z = f2b(b.z); o1.w = f2b(b.w);
  *(ushort4*)(dst + i) = o0;
  *(ushort4*)(dst + i + 4) = o1;
}

// ---------------- router: fp32 logits, softmax, top-2, renorm; fused x->bf16 ----------------
__global__ __launch_bounds__(256) void router_k(
    const float* __restrict__ x, const float* __restrict__ gw,
    float* __restrict__ topkw, int* __restrict__ topke, int* __restrict__ counts,
    float* __restrict__ logits_out, unsigned short* __restrict__ xb)
{
  int wave = threadIdx.x >> 6, lane = threadIdx.x & 63;
  int t = blockIdx.x * 4 + wave;
  const float* xr = x + (size_t)t * DIM;
  unsigned short* xbr = xb + (size_t)t * DIM;
  float acc[NE];
#pragma unroll
  for (int e = 0; e < NE; e++) acc[e] = 0.f;
  for (int d = lane * 4; d < DIM; d += 256) {
    float4 xv = *(const float4*)(xr + d);
    ushort4 xo;
    xo.x = f2b(xv.x); xo.y = f2b(xv.y); xo.z = f2b(xv.z); xo.w = f2b(xv.w);
    *(ushort4*)(xbr + d) = xo;
#pragma unroll
    for (int e = 0; e < NE; e++) {
      float4 gv = *(const float4*)(gw + e * DIM + d);
      acc[e] += xv.x * gv.x + xv.y * gv.y + xv.z * gv.z + xv.w * gv.w;
    }
  }
#pragma unroll
  for (int off = 32; off > 0; off >>= 1) {
#pragma unroll
    for (int e = 0; e < NE; e++) acc[e] += __shfl_down(acc[e], off);
  }
  if (lane == 0) {
    float m = acc[0];
#pragma unroll
    for (int e = 1; e < NE; e++) m = fmaxf(m, acc[e]);
    float p[NE];
#pragma unroll
    for (int e = 0; e < NE; e++) p[e] = __expf(acc[e] - m);
    int e0 = 0;
#pragma unroll
    for (int e = 1; e < NE; e++) if (acc[e] > acc[e0]) e0 = e;
    int e1 = -1;
#pragma unroll
    for (int e = 0; e < NE; e++) if (e != e0 && (e1 < 0 || acc[e] > acc[e1])) e1 = e;
    float s = p[e0] + p[e1];
    topkw[t * 2] = p[e0] / s;
    topkw[t * 2 + 1] = p[e1] / s;
    topke[t * 2] = e0; topke[t * 2 + 1] = e1;
    atomicAdd(&counts[e0], 1);
    atomicAdd(&counts[e1], 1);
#pragma unroll
    for (int e = 0; e < NE; e++) logits_out[t * NE + e] = acc[e];
  }
}

// ---------------- scan: offsets, cursors, tile table ----------------
__global__ void scan_k(const int* __restrict__ counts, int* __restrict__ offsets,
                       int* __restrict__ cursors, int4* __restrict__ tiles,
                       int* __restrict__ ntiles)
{
  if (threadIdx.x == 0 && blockIdx.x == 0) {
    int o = 0, nt = 0;
    for (int e = 0; e < NE; e++) {
      offsets[e] = o; cursors[e] = o;
      int c = counts[e];
      for (int r = 0; r < c; r += 128) {
        int rows = c - r < 128 ? c - r : 128;
        tiles[nt] = make_int4(e, o + r, rows, 0);
        nt++;
      }
      o += c;
    }
    offsets[NE] = o;
    *ntiles = nt;
  }
}

// ---------------- scatter: (t,k) -> sorted slot ----------------
__global__ void scatter_k(const int* __restrict__ topke, int* __restrict__ cursors,
                          int* __restrict__ perm)
{
  int i = blockIdx.x * blockDim.x + threadIdx.x;
  int e = topke[i];
  int s = atomicAdd(&cursors[e], 1);
  perm[s] = i;
}

// ================= bf16-weight path (primary, 2-phase double-buffered) =================

// GEMM1: H[slot,f] = rw * silu(x@Wg^T) * (x@Wu^T)
__global__ __launch_bounds__(256) void gemm1_bf_k(
    const unsigned short* __restrict__ xb,
    const unsigned short* __restrict__ wgb,
    const unsigned short* __restrict__ wub,
    const int* __restrict__ perm, const float* __restrict__ topkw,
    const int4* __restrict__ tiles, const int* __restrict__ ntiles,
    unsigned short* __restrict__ H)
{
  __shared__ short As[2][128 * 32];
  __shared__ short Bgs[2][64 * 32];
  __shared__ short Bus[2][64 * 32];
  __shared__ int rowtok[128];
  __shared__ float roww[128];

  if (blockIdx.x >= *ntiles) return;
  int4 tm = tiles[blockIdx.x];
  int e = tm.x, row0 = tm.y, nrows = tm.z;
  int tid = threadIdx.x;
  if (tid < 128) {
    int r = tid < nrows ? tid : (nrows - 1);
    int pid = perm[row0 + r];
    rowtok[tid] = pid >> 1;
    roww[tid] = topkw[pid];
  }
  __syncthreads();

  int f0 = blockIdx.y * 64;
  int crow = tid >> 2;            // 0..63
  int ccol = (tid & 3) * 8;       // 8-elem chunk offset
  const unsigned short* a0 = xb + (size_t)rowtok[crow] * DIM + ccol;
  const unsigned short* a1 = xb + (size_t)rowtok[crow + 64] * DIM + ccol;
  const unsigned short* bg = wgb + ((size_t)e * FDIM + f0 + crow) * DIM + ccol;
  const unsigned short* bu = wub + ((size_t)e * FDIM + f0 + crow) * DIM + ccol;

  int wave = tid >> 6, lane = tid & 63;
  int wm = wave >> 1, wn = wave & 1;
  int lrow = lane & 15, quad = lane >> 4;

  f32x4 accg[4][2], accu[4][2];
#pragma unroll
  for (int i = 0; i < 4; i++)
#pragma unroll
    for (int j = 0; j < 2; j++) {
      accg[i][j] = (f32x4){0.f, 0.f, 0.f, 0.f};
      accu[i][j] = (f32x4){0.f, 0.f, 0.f, 0.f};
    }

  const int aoff = (wm * 64 + lrow) * 32 + quad * 8;
  const int boff = (wn * 32 + lrow) * 32 + quad * 8;

#define STAGE1(b, k)                                 \
  do {                                               \
    async16(&As[b][tid * 8], a0 + (k));              \
    async16(&As[b][(256 + tid) * 8], a1 + (k));      \
    async16(&Bgs[b][tid * 8], bg + (k));             \
    async16(&Bus[b][tid * 8], bu + (k));             \
  } while (0)

  STAGE1(0, 0);

#pragma unroll 1
  for (int k0 = 0; k0 < DIM; k0 += 32) {
    int b = (k0 >> 5) & 1;
    __syncthreads();                       // buf b ready (vmcnt drained by barrier)
    if (k0 + 32 < DIM) STAGE1(b ^ 1, k0 + 32);   // issue next; overlaps MFMA below
    const short* arp = &As[0][0] + b * (128 * 32) + aoff;
    const short* bgp = &Bgs[0][0] + b * (64 * 32) + boff;
    const short* bup = &Bus[0][0] + b * (64 * 32) + boff;
    short8 af[4], bgf[2], buf2[2];
#pragma unroll
    for (int i = 0; i < 4; i++) af[i] = *(const short8*)(arp + i * 16 * 32);
#pragma unroll
    for (int j = 0; j < 2; j++) {
      bgf[j]  = *(const short8*)(bgp + j * 16 * 32);
      buf2[j] = *(const short8*)(bup + j * 16 * 32);
    }
#pragma unroll
    for (int i = 0; i < 4; i++)
#pragma unroll
      for (int j = 0; j < 2; j++) {
        accg[i][j] = __builtin_amdgcn_mfma_f32_16x16x32_bf16(af[i], bgf[j], accg[i][j], 0, 0, 0);
        accu[i][j] = __builtin_amdgcn_mfma_f32_16x16x32_bf16(af[i], buf2[j], accu[i][j], 0, 0, 0);
      }
  }
#undef STAGE1

#pragma unroll
  for (int i = 0; i < 4; i++) {
#pragma unroll
    for (int reg = 0; reg < 4; reg++) {
      int r = wm * 64 + i * 16 + quad * 4 + reg;
      if (r < nrows) {
        float w = roww[r];
#pragma unroll
        for (int j = 0; j < 2; j++) {
          float g = accg[i][j][reg], u = accu[i][j][reg];
          float h = g * u * w / (1.f + __expf(-g));
          H[(size_t)(row0 + r) * FDIM + f0 + wn * 32 + j * 16 + lrow] = f2b(h);
        }
      }
    }
  }
}

// GEMM2: out[t,d] += H[slot,:] @ Wd[e]^T  (128x128 tile, fp32 atomics)
__global__ __launch_bounds__(256) void gemm2_bf_k(
    const unsigned short* __restrict__ H,
    const unsigned short* __restrict__ wdb,
    const int* __restrict__ perm,
    const int4* __restrict__ tiles, const int* __restrict__ ntiles,
    float* __restrict__ out)
{
  __shared__ short Hs[2][128 * 32];
  __shared__ short Bs[2][128 * 32];
  __shared__ int rowtok[128];

  if (blockIdx.x >= *ntiles) return;
  int4 tm = tiles[blockIdx.x];
  int e = tm.x, row0 = tm.y, nrows = tm.z;
  int tid = threadIdx.x;
  if (tid < 128) {
    int r = tid < nrows ? tid : (nrows - 1);
    rowtok[tid] = perm[row0 + r] >> 1;
  }
  __syncthreads();

  int d0 = blockIdx.y * 128;
  int crow = tid >> 2, ccol = (tid & 3) * 8;
  const unsigned short* a0 = H + (size_t)(row0 + crow) * FDIM + ccol;
  const unsigned short* a1 = H + (size_t)(row0 + crow + 64) * FDIM + ccol;
  const unsigned short* b0 = wdb + ((size_t)e * DIM + d0 + crow) * FDIM + ccol;
  const unsigned short* b1 = b0 + (size_t)64 * FDIM;

  int wave = tid >> 6, lane = tid & 63;
  int wm = wave >> 1, wn = wave & 1;
  int lrow = lane & 15, quad = lane >> 4;

  f32x4 acc[4][4];
#pragma unroll
  for (int i = 0; i < 4; i++)
#pragma unroll
    for (int j = 0; j < 4; j++) acc[i][j] = (f32x4){0.f, 0.f, 0.f, 0.f};

  const int aoff = (wm * 64 + lrow) * 32 + quad * 8;
  const int boff = (wn * 64 + lrow) * 32 + quad * 8;

#define STAGE2(b, k)                                 \
  do {                                               \
    async16(&Hs[b][tid * 8], a0 + (k));              \
    async16(&Hs[b][(256 + tid) * 8], a1 + (k));      \
    async16(&Bs[b][tid * 8], b0 + (k));              \
    async16(&Bs[b][(256 + tid) * 8], b1 + (k));      \
  } while (0)

  STAGE2(0, 0);

#pragma unroll 1
  for (int k0 = 0; k0 < FDIM; k0 += 32) {
    int b = (k0 >> 5) & 1;
    __syncthreads();
    if (k0 + 32 < FDIM) STAGE2(b ^ 1, k0 + 32);
    const short* arp = &Hs[0][0] + b * (128 * 32) + aoff;
    const short* brp = &Bs[0][0] + b * (128 * 32) + boff;
    short8 af[4], bf[4];
#pragma unroll
    for (int i = 0; i < 4; i++) af[i] = *(const short8*)(arp + i * 16 * 32);
#pragma unroll
    for (int j = 0; j < 4; j++) bf[j] = *(const short8*)(brp + j * 16 * 32);
#pragma unroll
    for (int i = 0; i < 4; i++)
#pragma unroll
      for (int j = 0; j < 4; j++)
        acc[i][j] = __builtin_amdgcn_mfma_f32_16x16x32_bf16(af[i], bf[j], acc[i][j], 0, 0, 0);
  }
#undef STAGE2

#pragma unroll
  for (int i = 0; i < 4; i++) {
#pragma unroll
    for (int reg = 0; reg < 4; reg++) {
      int r = wm * 64 + i * 16 + quad * 4 + reg;
      if (r < nrows) {
        int t = rowtok[r];
#pragma unroll
        for (int j = 0; j < 4; j++) {
          atomicAdd(&out[(size_t)t * DIM + d0 + wn * 64 + j * 16 + lrow], acc[i][j][reg]);
        }
      }
    }
  }
}

// ================= fp32-weight fallback path (proven, used if ws too small) =================

__global__ __launch_bounds__(256) void gemm1_f32_k(
    const unsigned short* __restrict__ xb,
    const float* __restrict__ wg,
    const float* __restrict__ wu,
    const int* __restrict__ perm, const float* __restrict__ topkw,
    const int4* __restrict__ tiles, const int* __restrict__ ntiles,
    unsigned short* __restrict__ H)
{
  __shared__ short As[128 * 32];
  __shared__ short Bgs[64 * 32];
  __shared__ short Bus[64 * 32];
  __shared__ int rowtok[128];
  __shared__ float roww[128];

  if (blockIdx.x >= *ntiles) return;
  int4 tm = tiles[blockIdx.x];
  int e = tm.x, row0 = tm.y, nrows = tm.z;
  int tid = threadIdx.x;
  if (tid < 128) {
    int r = tid < nrows ? tid : (nrows - 1);
    int pid = perm[row0 + r];
    rowtok[tid] = pid >> 1;
    roww[tid] = topkw[pid];
  }
  __syncthreads();

  int f0 = blockIdx.y * 64;
  int crow = tid >> 2;
  int ccol = (tid & 3) * 8;
  const unsigned short* a0 = xb + (size_t)rowtok[crow] * DIM + ccol;
  const unsigned short* a1 = xb + (size_t)rowtok[crow + 64] * DIM + ccol;
  const float* bg32 = wg + ((size_t)e * FDIM + f0 + crow) * DIM + ccol;
  const float* bu32 = wu + ((size_t)e * FDIM + f0 + crow) * DIM + ccol;
  short* as0 = As + tid * 8;
  short* as1 = As + (256 + tid) * 8;

  int wave = tid >> 6, lane = tid & 63;
  int wm = wave >> 1, wn = wave & 1;
  int lrow = lane & 15, quad = lane >> 4;

  f32x4 accg[4][2], accu[4][2];
#pragma unroll
  for (int i = 0; i < 4; i++)
#pragma unroll
    for (int j = 0; j < 2; j++) {
      accg[i][j] = (f32x4){0.f, 0.f, 0.f, 0.f};
      accu[i][j] = (f32x4){0.f, 0.f, 0.f, 0.f};
    }

  const short* arp = As + (wm * 64 + lrow) * 32 + quad * 8;
  const short* bgp = Bgs + (wn * 32 + lrow) * 32 + quad * 8;
  const short* bup = Bus + (wn * 32 + lrow) * 32 + quad * 8;

#pragma unroll 1
  for (int k0 = 0; k0 < DIM; k0 += 32) {
    async16(as0, a0 + k0);
    async16(as1, a1 + k0);
    float4 g0 = *(const float4*)(bg32 + k0);
    float4 g1 = *(const float4*)(bg32 + k0 + 4);
    float4 u0 = *(const float4*)(bu32 + k0);
    float4 u1 = *(const float4*)(bu32 + k0 + 4);
    short8 gs, us;
    gs[0] = f2b(g0.x); gs[1] = f2b(g0.y); gs[2] = f2b(g0.z); gs[3] = f2b(g0.w);
    gs[4] = f2b(g1.x); gs[5] = f2b(g1.y); gs[6] = f2b(g1.z); gs[7] = f2b(g1.w);
    us[0] = f2b(u0.x); us[1] = f2b(u0.y); us[2] = f2b(u0.z); us[3] = f2b(u0.w);
    us[4] = f2b(u1.x); us[5] = f2b(u1.y); us[6] = f2b(u1.z); us[7] = f2b(u1.w);
    *(short8*)(Bgs + tid * 8) = gs;
    *(short8*)(Bus + tid * 8) = us;
    __syncthreads();
    short8 af[4], bgf[2], buf2[2];
#pragma unroll
    for (int i = 0; i < 4; i++) af[i] = *(const short8*)(arp + i * 16 * 32);
#pragma unroll
    for (int j = 0; j < 2; j++) {
      bgf[j]  = *(const short8*)(bgp + j * 16 * 32);
      buf2[j] = *(const short8*)(bup + j * 16 * 32);
    }
#pragma unroll
    for (int i = 0; i < 4; i++)
#pragma unroll
      for (int j = 0; j < 2; j++) {
        accg[i][j] = __builtin_amdgcn_mfma_f32_16x16x32_bf16(af[i], bgf[j], accg[i][j], 0, 0, 0);
        accu[i][j] = __builtin_amdgcn_mfma_f32_16x16x32_bf16(af[i], buf2[j], accu[i][j], 0, 0, 0);
      }
    __syncthreads();
  }

#pragma unroll
  for (int i = 0; i < 4; i++) {
#pragma unroll
    for (int reg = 0; reg < 4; reg++) {
      int r = wm * 64 + i * 16 + quad * 4 + reg;
      if (r < nrows) {
        float w = roww[r];
#pragma unroll
        for (int j = 0; j < 2; j++) {
          float g = accg[i][j][reg], u = accu[i][j][reg];
          float h = g * u * w / (1.f + __expf(-g));
          H[(size_t)(row0 + r) * FDIM + f0 + wn * 32 + j * 16 + lrow] = f2b(h);
        }
      }
    }
  }
}

__global__ __launch_bounds__(256) void gemm2_f32_k(
    const unsigned short* __restrict__ H,
    const float* __restrict__ wd,
    const int* __restrict__ perm,
    const int4* __restrict__ tiles, const int* __restrict__ ntiles,
    float* __restrict__ out)
{
  __shared__ short Hs[128 * 32];
  __shared__ short Bs[64 * 32];
  __shared__ int rowtok[128];

  if (blockIdx.x >= *ntiles) return;
  int4 tm = tiles[blockIdx.x];
  int e = tm.x, row0 = tm.y, nrows = tm.z;
  int tid = threadIdx.x;
  if (tid < 128) {
    int r = tid < nrows ? tid : (nrows - 1);
    rowtok[tid] = perm[row0 + r] >> 1;
  }
  __syncthreads();

  int d0 = blockIdx.y * 64;
  int crow = tid >> 2, ccol = (tid & 3) * 8;
  const unsigned short* a0 = H + (size_t)(row0 + crow) * FDIM + ccol;
  const unsigned short* a1 = H + (size_t)(row0 + crow + 64) * FDIM + ccol;
  const float* b32 = wd + ((size_t)e * DIM + d0 + crow) * FDIM + ccol;
  short* hs0 = Hs + tid * 8;
  short* hs1 = Hs + (256 + tid) * 8;

  int wave = tid >> 6, lane = tid & 63;
  int wm = wave >> 1, wn = wave & 1;
  int lrow = lane & 15, quad = lane >> 4;

  f32x4 acc[4][2];
#pragma unroll
  for (int i = 0; i < 4; i++)
#pragma unroll
    for (int j = 0; j < 2; j++) acc[i][j] = (f32x4){0.f, 0.f, 0.f, 0.f};

  const short* arp = Hs + (wm * 64 + lrow) * 32 + quad * 8;
  const short* brp = Bs + (wn * 32 + lrow) * 32 + quad * 8;

#pragma unroll 1
  for (int k0 = 0; k0 < FDIM; k0 += 32) {
    async16(hs0, a0 + k0);
    async16(hs1, a1 + k0);
    float4 b0 = *(const float4*)(b32 + k0);
    float4 b1 = *(const float4*)(b32 + k0 + 4);
    short8 bsv;
    bsv[0] = f2b(b0.x); bsv[1] = f2b(b0.y); bsv[2] = f2b(b0.z); bsv[3] = f2b(b0.w);
    bsv[4] = f2b(b1.x); bsv[5] = f2b(b1.y); bsv[6] = f2b(b1.z); bsv[7] = f2b(b1.w);
    *(short8*)(Bs + tid * 8) = bsv;
    __syncthreads();
    short8 af[4], bf[2];
#pragma unroll
    for (int i = 0; i < 4; i++) af[i] = *(const short8*)(arp + i * 16 * 32);
#pragma unroll
    for (int j = 0; j < 2; j++) bf[j] = *(const short8*)(brp + j * 16 * 32);
#pragma unroll
    for (int i = 0; i < 4; i++)
#pragma unroll
      for (int j = 0; j < 2; j++)
        acc[i][j] = __builtin_amdgcn_mfma_f32_16x16x32_bf16(af[i], bf[j], acc[i][j], 0, 0, 0);
    __syncthreads();
  }

#pragma unroll
  for (int i = 0; i < 4; i++) {
#pragma unroll
    for (int reg = 0; reg < 4; reg++) {
      int r = wm * 64 + i * 16 + quad * 4 + reg;
      if (r < nrows) {
        int t = rowtok[r];
#pragma unroll
        for (int j = 0; j < 2; j++) {
          atomicAdd(&out[(size_t)t * DIM + d0 + wn * 32 + j * 16 + lrow], acc[i][j][reg]);
        }
      }
    }
  }
}

extern "C" void kernel_launch(void* const* d_in, const int* in_sizes, int n_in,
                              void* d_out, int out_size, void* d_ws, size_t ws_size,
                              hipStream_t stream)
{
  const float* x  = (const float*)d_in[0];
  const float* gw = (const float*)d_in[1];
  const float* wg = (const float*)d_in[2];
  const float* wu = (const float*)d_in[3];
  const float* wd = (const float*)d_in[4];
  float* out = (float*)d_out;
  float* logits_out = out + (size_t)T_TOK * DIM;

  char* ws = (char*)d_ws;
  float* topkw   = (float*)(ws + 0);                 // 16 KB
  int*   topke   = (int*)(ws + 16384);               // 16 KB
  int*   counts  = (int*)(ws + 32768);
  int*   offsets = (int*)(ws + 32768 + 64);
  int*   cursors = (int*)(ws + 32768 + 128);
  int*   ntiles  = (int*)(ws + 32768 + 192);
  int4*  tiles   = (int4*)(ws + 32768 + 256);        // <= 40 * 16 B
  int*   perm    = (int*)(ws + 32768 + 2048);        // 16 KB
  unsigned short* xb  = (unsigned short*)(ws + (1u << 16));      // 8 MiB bf16 x @64KiB
  unsigned short* H   = (unsigned short*)(ws + (9u  << 20));     // 8.65 MiB @9MiB
  unsigned short* wgb = (unsigned short*)(ws + (18u << 20));     // 32 MiB @18MiB
  unsigned short* wub = (unsigned short*)(ws + (50u << 20));     // 32 MiB @50MiB
  unsigned short* wdb = wgb;   // aliases wgb: gate weights dead after gemm1
  const size_t WS_NEED = (size_t)82u << 20;

  // d_out is poisoned (0xAA) before timed replays -> zero it ourselves.
  hipMemsetAsync(d_out, 0, (size_t)out_size * sizeof(float), stream);
  hipMemsetAsync(counts, 0, 64, stream);

  router_k<<<T_TOK / 4, 256, 0, stream>>>(x, gw, topkw, topke, counts, logits_out, xb);
  scan_k<<<1, 64, 0, stream>>>(counts, offsets, cursors, tiles, ntiles);
  scatter_k<<<(T_TOK * 2) / 256, 256, 0, stream>>>(topke, cursors, perm);

  if (ws_size >= WS_NEED) {
    const int nblk = (NE * FDIM * DIM) / 2048;   // 8192 blocks per weight tensor
    cvt_w_k<<<nblk, 256, 0, stream>>>(wg, wgb);
    cvt_w_k<<<nblk, 256, 0, stream>>>(wu, wub);
    gemm1_bf_k<<<dim3(MAXTILES, FDIM / 64), 256, 0, stream>>>(xb, wgb, wub, perm, topkw, tiles, ntiles, H);
    // wd conversion stream-ordered AFTER gemm1 (wdb aliases wgb)
    cvt_w_k<<<nblk, 256, 0, stream>>>(wd, wdb);
    gemm2_bf_k<<<dim3(MAXTILES, DIM / 128), 256, 0, stream>>>(H, wdb, perm, tiles, ntiles, out);
  } else {
    gemm1_f32_k<<<dim3(MAXTILES, FDIM / 64), 256, 0, stream>>>(xb, wg, wu, perm, topkw, tiles, ntiles, H);
    gemm2_f32_k<<<dim3(MAXTILES, DIM / 64), 256, 0, stream>>>(H, wd, perm, tiles, ntiles, out);
  }
}